// Round 9
// baseline (89.988 us; speedup 1.0000x reference)
//
#include <hip/hip_runtime.h>
#include <hip/hip_bf16.h>

// Problem dims (fixed by the reference)
#define N_DIM 32
#define C_DIM 64
#define T_DIM 512
#define V_DIM 25
#define H_DIM 3
#define TT 8                              // t-values per block (one t-group)
#define NBLK1 2048                        // pass1 blocks (8 per CU, 4 resident)
#define NTGRP 2048                        // pass3 blocks (8-t groups)
#define NTV (N_DIM * T_DIM * V_DIM)       // 409600 elements per channel
#define NTOT (N_DIM * C_DIM * T_DIM * V_DIM)
#define XPITCH 76                         // shorts per tu-row (152 B)
#define XROWS 208                         // 200 data rows + 8 zero-pad
#define TILE_SH 1792                      // shorts per (n,t) scratch tile (3584 B)
#define SITER 13                          // staging iters (3200 / 256, ceil)
#define BN_EPS 1e-5f

typedef float f32x4 __attribute__((ext_vector_type(4)));
typedef short bf16x8 __attribute__((ext_vector_type(8)));
typedef short s16x4 __attribute__((ext_vector_type(4)));

__device__ __forceinline__ short f2bf(float f) {
    __hip_bfloat16 h = __float2bfloat16(f);   // RNE; pairs fuse to v_cvt_pk_bf16_f32
    return __builtin_bit_cast(short, h);
}
__device__ __forceinline__ float bf2f(short s) {
    return __uint_as_float(((unsigned)(unsigned short)s) << 16);
}

__device__ __forceinline__ bf16x8 ld_bf8(const short* p) {   // two b64 LDS reads
    s16x4 a = *(const s16x4*)p;
    s16x4 b = *(const s16x4*)(p + 4);
    bf16x8 r;
    r[0] = a[0]; r[1] = a[1]; r[2] = a[2]; r[3] = a[3];
    r[4] = b[0]; r[5] = b[1]; r[6] = b[2]; r[7] = b[3];
    return r;
}

// ---------------------------------------------------------------------------
// Pass 0: pack W and A into per-thread MFMA fragment layout (bf16).
// wpack[b=h*2+s][tid] : o = 16*(tid>>6)+(tid&15), c = s*32+((tid>>4)&3)*8+i
// apack[b=h*2+vt][tid]: v = vt*16+(tid&15),       u = ((tid>>4)&3)*8+i  (0-pad)
// ---------------------------------------------------------------------------
__global__ __launch_bounds__(256) void gcn_pack(
    const float* __restrict__ A, const float* __restrict__ W,
    short* __restrict__ wpack, short* __restrict__ apack)
{
    const int b   = blockIdx.x;           // 0..11
    const int tid = threadIdx.x;
    const int l15 = tid & 15, hi = (tid >> 4) & 3, w = tid >> 6;
    if (b < 6) {
        int h = b >> 1, s = b & 1;
        const float* wp = W + h * 4096 + (16 * w + l15) * 64 + s * 32 + hi * 8;
        bf16x8 f;
        #pragma unroll
        for (int i = 0; i < 8; ++i) f[i] = f2bf(wp[i]);
        *(bf16x8*)(wpack + ((size_t)b * 256 + tid) * 8) = f;
    } else {
        int bb = b - 6, h = bb >> 1, vt = bb & 1;
        int v = vt * 16 + l15;
        bf16x8 f;
        #pragma unroll
        for (int i = 0; i < 8; ++i) {
            int u = hi * 8 + i;
            f[i] = (v < 25 && u < 25) ? f2bf(A[h * 625 + v * 25 + u]) : (short)0;
        }
        *(bf16x8*)(apack + ((size_t)bb * 256 + tid) * 8) = f;
    }
}

// ---- issue-early: launch the t-group's 52 global loads into registers
__device__ __forceinline__ void stage_load(float (&fr)[SITER][4],
                                           const float* __restrict__ xg, int tid)
{
    #pragma unroll
    for (int k = 0; k < SITER; ++k) {
        int e = tid + k * 256;
        if (k < SITER - 1 || e < 3200) {
            int cg = e / 200, tu = e - cg * 200;
            const float* p = xg + cg * 51200 + tu;   // 4 c-rows per cg
            fr[k][0] = p[0];
            fr[k][1] = p[12800];
            fr[k][2] = p[25600];
            fr[k][3] = p[38400];
        }
    }
}
// ---- write-late: vmcnt drains here, then convert + coalesced ds_write
__device__ __forceinline__ void stage_write(const float (&fr)[SITER][4],
                                            short* __restrict__ dst, int tid)
{
    #pragma unroll
    for (int k = 0; k < SITER; ++k) {
        int e = tid + k * 256;
        if (k < SITER - 1 || e < 3200) {
            int cg = e / 200, tu = e - cg * 200;
            s16x4 v; v[0] = f2bf(fr[k][0]); v[1] = f2bf(fr[k][1]);
                     v[2] = f2bf(fr[k][2]); v[3] = f2bf(fr[k][3]);
            *(s16x4*)&dst[tu * XPITCH + 4 * cg] = v;
        }
    }
}

// ---------------------------------------------------------------------------
// Pass 1 (register-fused MFMA, ONE t-group per block, max TLP):
//   out_pre[n,o,t,v] = sum_{h,c,u} W[h,o,c] A[h,v,u] x[n,c,t,u]
// GEMM1 per (t,uh): D1[u'][o] = mfma(A=x rows u', B=W cols o), K=c=64; the
//   u-permutation u(m) = (m>>2)*8 + uh*4 + (m&3) makes lane (l15,hi) hold
//   y[u=hi*8+uh*4+j][o=l15] — exactly GEMM2's B-fragment, in registers.
// GEMM2 per t: acc[v][o] += mfma(A = A_h rows v, B = y-frag), K=u pad 32.
// Single 31.6 KB LDS buffer + __launch_bounds__(256,4) -> 4 blocks/CU
// resident (16 waves/CU): staging latency of one block hides under other
// blocks' MFMA phases (TLP, not ILP — R8 evidence says ILP alone can't).
// SCR=1: wave-linear bf16 scratch tiles [n][t_abs] (coalesced 8B stores).
// SCR=0: fp32 direct to d_out (fallback; in-kernel fragment build).
// bias dropped: per-channel constant cancels exactly through BatchNorm.
// ---------------------------------------------------------------------------
template <int SCR>
__global__ __launch_bounds__(256, 4) void gcn_pass1(
    const float* __restrict__ x, const float* __restrict__ A,
    const float* __restrict__ W, const short* __restrict__ wpack,
    const short* __restrict__ apack, void* __restrict__ scratch_,
    float* __restrict__ partial)
{
    __shared__ __align__(16) short x_sT[XROWS * XPITCH];   // 31,616 B

    const int bid  = blockIdx.x;           // 0..2047
    const int n    = bid >> 6;
    const int tgrp = bid & 63;
    const int tid  = threadIdx.x;
    const int lane = tid & 63;
    const int w    = tid >> 6;             // wave 0..3 -> o in [16w, 16w+16)
    const int l15  = lane & 15;
    const int hi   = lane >> 4;

    // ---- stage this block's x tile: issue loads first, drain+write after
    {
        float fr[SITER][4];
        stage_load(fr, x + (size_t)n * 819200 + tgrp * (TT * 25), tid);
        // zero pad rows 200..207 while loads fly
        for (int e = tid; e < 304; e += 256)
            ((int*)&x_sT[200 * XPITCH])[e] = 0;
        stage_write(fr, &x_sT[0], tid);
    }

    bf16x8 wf[H_DIM][2], af[H_DIM][2];
    if constexpr (SCR) {
        #pragma unroll
        for (int h = 0; h < H_DIM; ++h)
            #pragma unroll
            for (int s = 0; s < 2; ++s) {
                wf[h][s] = *(const bf16x8*)(wpack + ((h * 2 + s) * 256 + tid) * 8);
                af[h][s] = *(const bf16x8*)(apack + ((h * 2 + s) * 256 + tid) * 8);
            }
    } else {
        #pragma unroll
        for (int h = 0; h < H_DIM; ++h)
            #pragma unroll
            for (int s = 0; s < 2; ++s) {
                const f32x4* wp = (const f32x4*)(W + h * 4096 + (16 * w + l15) * 64
                                                 + s * 32 + hi * 8);
                f32x4 lo = wp[0], hv = wp[1];
                bf16x8 f;
                #pragma unroll
                for (int i = 0; i < 4; ++i) { f[i] = f2bf(lo[i]); f[4+i] = f2bf(hv[i]); }
                wf[h][s] = f;
                int v = s * 16 + l15;
                bf16x8 g;
                #pragma unroll
                for (int i = 0; i < 8; ++i) {
                    int u = hi * 8 + i;
                    g[i] = (v < 25 && u < 25) ? f2bf(A[h * 625 + v * 25 + u]) : (short)0;
                }
                af[h][s] = g;
            }
    }
    __syncthreads();

    // per-lane x-row base for the u-permutation: u = (l15>>2)*8 + uh*4 + (l15&3)
    const int ubase = ((l15 >> 2) * 8) + (l15 & 3);
    const int o_glob = 16 * w + l15;
    float s_tot = 0.f, q_tot = 0.f;

    #pragma unroll 2
    for (int t = 0; t < TT; ++t) {
        const short* xr0 = &x_sT[(t * 25 + ubase + 0) * XPITCH + hi * 8];
        const short* xr1 = &x_sT[(t * 25 + ubase + 4) * XPITCH + hi * 8];
        const bf16x8 xf00 = ld_bf8(xr0), xf01 = ld_bf8(xr0 + 32);
        const bf16x8 xf10 = ld_bf8(xr1), xf11 = ld_bf8(xr1 + 32);

        f32x4 acc2[2] = {f32x4{0.f,0.f,0.f,0.f}, f32x4{0.f,0.f,0.f,0.f}};

        #pragma unroll
        for (int h = 0; h < H_DIM; ++h) {
            f32x4 y0 = {0.f,0.f,0.f,0.f}, y1 = {0.f,0.f,0.f,0.f};
            y0 = __builtin_amdgcn_mfma_f32_16x16x32_bf16(xf00, wf[h][0], y0, 0,0,0);
            y0 = __builtin_amdgcn_mfma_f32_16x16x32_bf16(xf01, wf[h][1], y0, 0,0,0);
            y1 = __builtin_amdgcn_mfma_f32_16x16x32_bf16(xf10, wf[h][0], y1, 0,0,0);
            y1 = __builtin_amdgcn_mfma_f32_16x16x32_bf16(xf11, wf[h][1], y1, 0,0,0);
            bf16x8 yf;
            #pragma unroll
            for (int j = 0; j < 4; ++j) yf[j] = f2bf(y0[j]);
            #pragma unroll
            for (int j = 0; j < 4; ++j) yf[4 + j] = f2bf(y1[j]);
            acc2[0] = __builtin_amdgcn_mfma_f32_16x16x32_bf16(af[h][0], yf, acc2[0], 0,0,0);
            acc2[1] = __builtin_amdgcn_mfma_f32_16x16x32_bf16(af[h][1], yf, acc2[1], 0,0,0);
        }

        if (SCR) {
            // wave-linear bf16 tile [n][t_abs]: two coalesced 8B stores
            short* base = (short*)scratch_
                        + ((size_t)(n * 512 + tgrp * TT + t)) * TILE_SH;
            s16x4 p0; p0[0]=f2bf(acc2[0][0]); p0[1]=f2bf(acc2[0][1]);
                      p0[2]=f2bf(acc2[0][2]); p0[3]=f2bf(acc2[0][3]);
            *(s16x4*)(base + w * 256 + hi * 64 + l15 * 4) = p0;
            if (hi < 3) {
                s16x4 p1; p1[0]=f2bf(acc2[1][0]); p1[1]=f2bf(acc2[1][1]);
                          p1[2]=f2bf(acc2[1][2]); p1[3]=f2bf(acc2[1][3]);
                *(s16x4*)(base + 1024 + w * 192 + hi * 64 + l15 * 4) = p1;
            }
        } else {
            float* op = (float*)scratch_
                      + ((size_t)(n * 64 + o_glob) * 512 + tgrp * TT + t) * 25;
            #pragma unroll
            for (int j = 0; j < 4; ++j) op[hi * 4 + j] = acc2[0][j];
            if (hi < 2) {
                #pragma unroll
                for (int j = 0; j < 4; ++j) op[16 + hi * 4 + j] = acc2[1][j];
            } else if (hi == 2) {
                op[24] = acc2[1][0];
            }
        }

        // ---- per-lane stats accumulate (shuffle hoisted to epilogue)
        float s = acc2[0][0] + acc2[0][1] + acc2[0][2] + acc2[0][3];
        float qq = fmaf(acc2[0][0], acc2[0][0], fmaf(acc2[0][1], acc2[0][1],
                   fmaf(acc2[0][2], acc2[0][2], acc2[0][3] * acc2[0][3])));
        if (hi < 2) {
            #pragma unroll
            for (int j = 0; j < 4; ++j) {
                float v1 = acc2[1][j]; s += v1; qq = fmaf(v1, v1, qq);
            }
        } else if (hi == 2) {
            float v1 = acc2[1][0]; s += v1; qq = fmaf(v1, v1, qq);
        }
        s_tot += s; q_tot += qq;
    }

    s_tot += __shfl_xor(s_tot, 16); q_tot += __shfl_xor(q_tot, 16);
    s_tot += __shfl_xor(s_tot, 32); q_tot += __shfl_xor(q_tot, 32);
    if (hi == 0) {
        partial[bid * 128 + o_glob]      = s_tot;
        partial[bid * 128 + 64 + o_glob] = q_tot;
    }
}

// ---------------------------------------------------------------------------
// Pass 2: reduce partials -> per-channel mean and rsqrt(var+eps)
// ---------------------------------------------------------------------------
__global__ __launch_bounds__(256) void gcn_stats(
    const float* __restrict__ partial, float* __restrict__ stats)
{
    const int o = blockIdx.x;      // 64 blocks, one per channel
    const int tid = threadIdx.x;
    float s = 0.f, q = 0.f;
    for (int blk = tid; blk < NBLK1; blk += 256) {
        s += partial[blk * 128 + o];
        q += partial[blk * 128 + 64 + o];
    }
    __shared__ float rs[256], rq[256];
    rs[tid] = s; rq[tid] = q;
    __syncthreads();
    for (int off = 128; off > 0; off >>= 1) {
        if (tid < off) { rs[tid] += rs[tid + off]; rq[tid] += rq[tid + off]; }
        __syncthreads();
    }
    if (tid == 0) {
        float mean = rs[0] / (float)NTV;
        float var  = rq[0] / (float)NTV - mean * mean;   // biased, like jnp.var
        stats[o]      = mean;
        stats[64 + o] = rsqrtf(var + BN_EPS);
    }
}

// ---- XOR chunk swizzle (involution): spreads stride-128B readers over banks
__device__ __forceinline__ int swz16(int chunk) {
    return chunk ^ ((chunk >> 3) & 7);
}

// ---------------------------------------------------------------------------
// Pass 3: un-scatter via LDS + BN + residual + ReLU, fully coalesced float4.
// One block per 8-t group: int4-copy its 8 tiles (28,672 B) into LDS with a
// 16B-chunk XOR swizzle (kills the (vv>>2)*128B same-bank pattern), then
// stream 64 o-runs x 200 floats as float4 (x read / out write coalesced).
// ---------------------------------------------------------------------------
__global__ __launch_bounds__(256) void gcn_finalize_b(
    const float* __restrict__ x, const float* __restrict__ gamma,
    const float* __restrict__ beta, const float* __restrict__ stats,
    const short* __restrict__ scr, float* __restrict__ out)
{
    __shared__ __align__(16) short tl_s[8 * TILE_SH];   // 28,672 B
    const int bid  = blockIdx.x;           // 0..2047
    const int n    = bid >> 6;
    const int tgrp = bid & 63;
    const int tid  = threadIdx.x;

    const int4* src = (const int4*)(scr + (size_t)bid * 8 * TILE_SH);
    int4* dst4 = (int4*)tl_s;
    #pragma unroll
    for (int k = 0; k < 7; ++k) {
        int i = tid + k * 256;             // 0..1791 chunks
        dst4[swz16(i)] = src[i];
    }
    __syncthreads();

    const size_t obase = (size_t)n * 819200 + (size_t)tgrp * 200;
    #pragma unroll
    for (int k = 0; k < 13; ++k) {
        int fi = tid + k * 256;
        if (fi < 3200) {
            int o  = fi / 50;                 // 50 float4 per o-run
            int p  = (fi - o * 50) * 4;       // 0..196
            int tl = p / 25;
            int v0 = p - tl * 25;
            float gm = gamma[o] * stats[64 + o];
            float bc = beta[o] - gm * stats[o];
            size_t gidx = obase + (size_t)o * 12800 + p;
            float4 xv = *(const float4*)(x + gidx);
            float r[4];
            #pragma unroll
            for (int j = 0; j < 4; ++j) {
                int vv = v0 + j, tt = tl;
                if (vv >= 25) { vv -= 25; tt += 1; }
                int off = (vv < 16)
                    ? ((o >> 4) * 256 + (vv >> 2) * 64 + (o & 15) * 4 + (vv & 3))
                    : (1024 + (o >> 4) * 192 + ((vv - 16) >> 2) * 64
                       + (o & 15) * 4 + (vv & 3));
                int raw = tt * TILE_SH + off;
                int adr = swz16(raw >> 3) * 8 + (raw & 7);
                float pv = bf2f(tl_s[adr]);
                r[j] = fmaxf(fmaf(gm, pv, bc) + (&xv.x)[j], 0.f);
            }
            float4 o4; o4.x = r[0]; o4.y = r[1]; o4.z = r[2]; o4.w = r[3];
            *(float4*)(out + gidx) = o4;
        }
    }
}

// ---------------------------------------------------------------------------
// Pass 3 (fallback, fp32 scratch == out): in-place elementwise
// ---------------------------------------------------------------------------
__global__ __launch_bounds__(256) void gcn_finalize_f(
    const float* __restrict__ x, const float* __restrict__ gamma,
    const float* __restrict__ beta, const float* __restrict__ stats,
    float* __restrict__ out)
{
    const int total4 = NTOT / 4;
    for (int i = blockIdx.x * blockDim.x + threadIdx.x; i < total4;
         i += gridDim.x * blockDim.x) {
        int chan = ((i * 4) / (T_DIM * V_DIM)) & 63;
        float4 p  = ((const float4*)out)[i];
        float4 xv = ((const float4*)x)[i];
        float m = stats[chan], r = stats[64 + chan];
        float g = gamma[chan] * r;
        float bc = beta[chan] - g * m;
        p.x = fmaxf(fmaf(g, p.x, bc) + xv.x, 0.f);
        p.y = fmaxf(fmaf(g, p.y, bc) + xv.y, 0.f);
        p.z = fmaxf(fmaf(g, p.z, bc) + xv.z, 0.f);
        p.w = fmaxf(fmaf(g, p.w, bc) + xv.w, 0.f);
        ((float4*)out)[i] = p;
    }
}

extern "C" void kernel_launch(void* const* d_in, const int* in_sizes, int n_in,
                              void* d_out, int out_size, void* d_ws, size_t ws_size,
                              hipStream_t stream) {
    const float* x     = (const float*)d_in[0];
    const float* A     = (const float*)d_in[1];
    const float* W     = (const float*)d_in[2];
    // d_in[3] = b : unused — per-channel bias cancels exactly through BatchNorm
    const float* gamma = (const float*)d_in[4];
    const float* beta  = (const float*)d_in[5];
    float* out = (float*)d_out;

    const size_t scr_bytes   = (size_t)N_DIM * T_DIM * TILE_SH * 2;  // 58,720,256
    const size_t part_bytes  = (size_t)NBLK1 * 128 * 4;              // 1,048,576
    const size_t stats_bytes = 512;
    const size_t pack_bytes  = 2 * 6 * 256 * 8 * 2;                  // 49,152

    if (ws_size >= scr_bytes + part_bytes + stats_bytes + pack_bytes) {
        short* scr     = (short*)d_ws;
        float* partial = (float*)((char*)d_ws + scr_bytes);
        float* stats   = partial + NBLK1 * 128;
        short* wpack   = (short*)((char*)d_ws + scr_bytes + part_bytes + stats_bytes);
        short* apack   = wpack + 6 * 256 * 8;

        gcn_pack<<<12, 256, 0, stream>>>(A, W, wpack, apack);
        gcn_pass1<1><<<NBLK1, 256, 0, stream>>>(x, A, W, wpack, apack,
                                                (void*)scr, partial);
        gcn_stats<<<64, 256, 0, stream>>>(partial, stats);
        gcn_finalize_b<<<NTGRP, 256, 0, stream>>>(x, gamma, beta, stats, scr, out);
    } else {
        float* partial = (float*)d_ws;
        float* stats   = partial + NBLK1 * 128;
        gcn_pass1<0><<<NBLK1, 256, 0, stream>>>(x, A, W, nullptr, nullptr,
                                                (void*)out, partial);
        gcn_stats<<<64, 256, 0, stream>>>(partial, stats);
        gcn_finalize_f<<<2048, 256, 0, stream>>>(x, gamma, beta, stats, out);
    }
}